// Round 1
// baseline (364.411 us; speedup 1.0000x reference)
//
#include <hip/hip_runtime.h>
#include <hip/hip_bf16.h>

// Bradley-Terry loss: out = sum_{i!=j} W[i,j] * (logaddexp(b_i, b_j) - b_i)
// N = 8192, W is fp32 row-major, betas fp32, scalar fp32 output.
//
// Memory-bound: single 256 MB streaming read of W. betas (32 KB) staged in LDS
// per block. float4 loads, grid-stride, per-thread accumulate, wave shuffle
// reduce, one float atomicAdd per block.

#define BT_N 8192
#define BT_NV (BT_N / 4)          // float4s per row = 2048
#define BLOCK 256
#define GRID 2048                 // 2048 blocks * 256 thr * 32 iters * 4 = 64M elems
#define ITERS 32

__device__ __forceinline__ float bt_term(float w, float bi, float bj) {
    // logaddexp(bi,bj) - bi = max(bj - bi, 0) + log1p(exp(-|bi - bj|))
    float d  = bi - bj;
    float val = fmaxf(-d, 0.0f) + __logf(1.0f + __expf(-fabsf(d)));
    return w * val;
}

__global__ __launch_bounds__(BLOCK) void bt_kernel(const float* __restrict__ W,
                                                   const float* __restrict__ betas,
                                                   float* __restrict__ out) {
    __shared__ float sb[BT_N];          // 32 KB: all betas
    __shared__ float wavesum[BLOCK / 64];

    // Stage betas into LDS (coalesced float4 loads).
    {
        const float4* b4 = (const float4*)betas;
        float4* sb4 = (float4*)sb;
        #pragma unroll
        for (int t = threadIdx.x; t < BT_NV; t += BLOCK)
            sb4[t] = b4[t];
    }
    __syncthreads();

    const float4* W4 = (const float4*)W;
    const float4* sb4 = (const float4*)sb;
    const unsigned gstride = GRID * BLOCK;
    unsigned v = blockIdx.x * BLOCK + threadIdx.x;

    float acc = 0.0f;
    #pragma unroll 4
    for (int it = 0; it < ITERS; ++it, v += gstride) {
        float4 w = W4[(size_t)v];
        int i  = v >> 11;             // row   = v / 2048
        int jv = v & 2047;            // col-vec within row
        float  bi = sb[i];
        float4 bj = sb4[jv];
        int j0 = jv << 2;

        float t0 = bt_term(w.x, bi, bj.x);
        float t1 = bt_term(w.y, bi, bj.y);
        float t2 = bt_term(w.z, bi, bj.z);
        float t3 = bt_term(w.w, bi, bj.w);
        // exclude diagonal
        if (j0 + 0 == i) t0 = 0.0f;
        if (j0 + 1 == i) t1 = 0.0f;
        if (j0 + 2 == i) t2 = 0.0f;
        if (j0 + 3 == i) t3 = 0.0f;
        acc += (t0 + t1) + (t2 + t3);
    }

    // Wave-level reduction (64 lanes).
    #pragma unroll
    for (int off = 32; off > 0; off >>= 1)
        acc += __shfl_down(acc, off);

    if ((threadIdx.x & 63) == 0)
        wavesum[threadIdx.x >> 6] = acc;
    __syncthreads();

    if (threadIdx.x == 0) {
        float s = 0.0f;
        #pragma unroll
        for (int k = 0; k < BLOCK / 64; ++k) s += wavesum[k];
        atomicAdd(out, s);
    }
}

extern "C" void kernel_launch(void* const* d_in, const int* in_sizes, int n_in,
                              void* d_out, int out_size, void* d_ws, size_t ws_size,
                              hipStream_t stream) {
    const float* W     = (const float*)d_in[0];
    const float* betas = (const float*)d_in[1];
    float* out = (float*)d_out;

    hipMemsetAsync(out, 0, sizeof(float), stream);
    bt_kernel<<<GRID, BLOCK, 0, stream>>>(W, betas, out);
}

// Round 2
// 362.606 us; speedup vs baseline: 1.0050x; 1.0050x over previous
//
#include <hip/hip_runtime.h>
#include <hip/hip_bf16.h>

// Bradley-Terry loss: out = sum_{i!=j} W[i,j] * softplus(b_j - b_i)
//   (logaddexp(b_i,b_j) - b_i == log1p(exp(b_j-b_i)) == softplus(b_j-b_i))
// N = 8192, W fp32 row-major (256 MB streaming read — the roofline), betas fp32.
//
// Design: betas (exactly 32 KB) staged once per block into LDS -> 5 blocks/CU
// possible; GRID=1024 makes all blocks co-resident (4/CU), zero tail. Grid-
// strided float4 loads of W, unroll 8 for deep in-flight load queue, fp32
// accumulate -> wave shuffle reduce -> sb[] reused for wave partials -> one
// atomicAdd per block (1024 total).

#define BT_N 8192
#define BT_NV (BT_N / 4)          // float4s per row = 2048
#define BLOCK 256
#define GRID 1024                 // 1024*256 threads * 64 iters * 4 elems = 64M
#define ITERS 64

__device__ __forceinline__ float bt_term(float w, float bi, float bj) {
    // softplus(bj - bi), stable: max(bj-bi, 0) + log1p(exp(-|bi-bj|))
    float d   = bi - bj;
    float val = fmaxf(-d, 0.0f) + __logf(1.0f + __expf(-fabsf(d)));
    return w * val;
}

__global__ __launch_bounds__(BLOCK) void bt_kernel(const float* __restrict__ W,
                                                   const float* __restrict__ betas,
                                                   float* __restrict__ out) {
    __shared__ float sb[BT_N];          // exactly 32 KB -> keeps 5 blocks/CU legal

    // Stage betas into LDS (coalesced float4 loads).
    {
        const float4* b4 = (const float4*)betas;
        float4* sb4w = (float4*)sb;
        #pragma unroll
        for (int t = threadIdx.x; t < BT_NV; t += BLOCK)
            sb4w[t] = b4[t];
    }
    __syncthreads();

    const float4* W4  = (const float4*)W;
    const float4* sb4 = (const float4*)sb;
    const unsigned gstride = GRID * BLOCK;
    unsigned v = blockIdx.x * BLOCK + threadIdx.x;

    float acc = 0.0f;
    #pragma unroll 8
    for (int it = 0; it < ITERS; ++it, v += gstride) {
        float4 w = W4[(size_t)v];
        unsigned i  = v >> 11;          // row
        unsigned jv = v & 2047u;        // col-vec within row
        float  bi = sb[i];              // broadcast within wave (mostly)
        float4 bj = sb4[jv];            // ds_read_b128, conflict-free
        unsigned j0 = jv << 2;

        float t0 = bt_term(w.x, bi, bj.x);
        float t1 = bt_term(w.y, bi, bj.y);
        float t2 = bt_term(w.z, bi, bj.z);
        float t3 = bt_term(w.w, bi, bj.w);
        // exclude diagonal
        if (j0 + 0u == i) t0 = 0.0f;
        if (j0 + 1u == i) t1 = 0.0f;
        if (j0 + 2u == i) t2 = 0.0f;
        if (j0 + 3u == i) t3 = 0.0f;
        acc += (t0 + t1) + (t2 + t3);
    }

    // Wave-level reduction (64 lanes).
    #pragma unroll
    for (int off = 32; off > 0; off >>= 1)
        acc += __shfl_down(acc, off);

    // Reuse sb[0..3] for wave partials (keeps LDS at exactly 32 KB).
    __syncthreads();                    // all betas reads complete
    if ((threadIdx.x & 63) == 0)
        sb[threadIdx.x >> 6] = acc;
    __syncthreads();

    if (threadIdx.x == 0)
        atomicAdd(out, (sb[0] + sb[1]) + (sb[2] + sb[3]));
}

extern "C" void kernel_launch(void* const* d_in, const int* in_sizes, int n_in,
                              void* d_out, int out_size, void* d_ws, size_t ws_size,
                              hipStream_t stream) {
    const float* W     = (const float*)d_in[0];
    const float* betas = (const float*)d_in[1];
    float* out = (float*)d_out;

    hipMemsetAsync(out, 0, sizeof(float), stream);
    bt_kernel<<<GRID, BLOCK, 0, stream>>>(W, betas, out);
}